// Round 5
// baseline (229.235 us; speedup 1.0000x reference)
//
#include <hip/hip_runtime.h>
#include <hip/hip_fp16.h>

// ---------------------------------------------------------------------------
// SoftDecisionTreeEnsemble: N_TREES=15, DEPTH=3, INPUT_DIM=128, N_CLASSES=10
// R7: delete the x->LDS stage. R6's counters: conflicts 4.46M (linear A-gather
// was 2x-serialized), but more fundamentally per-CU x-read stuck at 2.7 B/cyc
// across ALL structures that staged x via global_load_lds + vmcnt drain.
// The MFMA A-fragment lane(lm,lq) = x[lm][32s+8lq..+7] is directly loadable
// as two global_load_dwordx4 per s -> x never touches LDS. Plain VGPR loads
// with compiler per-register waits are the proven 6.3TB/s path (m13, fills).
//   - LDS shrinks to per-wave 16x272B scratch (A->B->C transposes): 17.4KB.
//   - no DMA, no vmcnt choreography, no A-gather ds_read (conflicts gone).
//   - grid=4096 (one 64-row tile/block), launch_bounds(256,4): 16 waves/CU,
//     in-flight = 8 loads x 1KB x 16 waves = 128KB/CU.
//   - weights: per-nt 2-deep rotate, unroll 1 (R3 spill lesson, VGPR=44 in R6).
// ---------------------------------------------------------------------------

typedef float    f32x4 __attribute__((ext_vector_type(4)));
typedef _Float16 half8 __attribute__((ext_vector_type(8)));

#define TREES      15
#define IDIM       128
#define NCLS       10
#define NINT       7
#define NLVS       8
#define PER_TREE   (NINT*IDIM + NINT + NLVS*NCLS)   // 983
#define NODES      (TREES*NINT)                     // 105
#define NPAD       112                              // 7 n-tiles of 16
#define KPAD       128                              // leaf K padded
#define RSTR       272                              // scratch row stride bytes (136 halves)
#define WSTR       4352                             // per-wave scratch: 16 rows * 272B

// ---------------------------------------------------------------------------
// prep: wq[112][128] f16 (row g=7t+n, zero-padded), bq[112] f32 (zero-padded),
//       wbT[16][128] f16: wbT[c][8t+l] = softmax(leaf_logits[t][l])[c]*tw[t].
// Zero padding is load-bearing: padded nodes give z=0 -> sigmoid 0.5 ->
// garbage-free; padded leaf cols/classes contribute 0.
// ---------------------------------------------------------------------------
__global__ __launch_bounds__(256) void prep_kernel(const float* __restrict__ p,
                                                   _Float16* __restrict__ wq,
                                                   float* __restrict__ bq,
                                                   _Float16* __restrict__ wbT) {
    const int gid  = blockIdx.x * 256 + threadIdx.x;
    const int nthr = gridDim.x * 256;

    for (int i = gid; i < NPAD * IDIM; i += nthr) {
        int g = i >> 7, k = i & 127;
        float v = 0.f;
        if (g < NODES) {
            int t = g / NINT, n = g % NINT;
            v = p[t * PER_TREE + n * IDIM + k];
        }
        wq[i] = (_Float16)v;
    }
    for (int i = gid; i < NPAD; i += nthr) {
        float v = 0.f;
        if (i < NODES) {
            int t = i / NINT, n = i % NINT;
            v = p[t * PER_TREE + NINT * IDIM + n];
        }
        bq[i] = v;
    }
    const float* tl = p + TREES * PER_TREE;
    for (int i = gid; i < 16 * KPAD; i += nthr) {
        int c = i >> 7, k = i & 127;
        float v = 0.f;
        if (c < NCLS && k < TREES * NLVS) {
            int t = k >> 3, l = k & 7;
            const float* ll = p + t * PER_TREE + NINT * IDIM + NINT + l * NCLS;
            float mx = ll[0];
            #pragma unroll
            for (int j = 1; j < NCLS; ++j) mx = fmaxf(mx, ll[j]);
            float se = 0.f;
            #pragma unroll
            for (int j = 0; j < NCLS; ++j) se += __expf(ll[j] - mx);
            float lsm = __expf(ll[c] - mx) / se;

            float m2 = tl[0];
            #pragma unroll
            for (int j = 1; j < TREES; ++j) m2 = fmaxf(m2, tl[j]);
            float s2 = 0.f;
            #pragma unroll
            for (int j = 0; j < TREES; ++j) s2 += __expf(tl[j] - m2);
            float tw = __expf(tl[t] - m2) / s2;
            v = lsm * tw;
        }
        wbT[i] = (_Float16)v;
    }
}

// ---------------------------------------------------------------------------
__global__ __launch_bounds__(256, 4) void tree_main(const float* __restrict__ x,
                                                    const _Float16* __restrict__ wq,
                                                    const float* __restrict__ bq,
                                                    const _Float16* __restrict__ wbT,
                                                    float* __restrict__ out) {
    __shared__ __align__(16) char lds[4 * WSTR];    // 17408 B

    const int tid  = threadIdx.x;
    const int lane = tid & 63;
    const int w    = tid >> 6;        // wave id: owns tile rows 16w..16w+15
    const int lm   = lane & 15;
    const int lq   = lane >> 4;
    const int rg   = lane >> 2;       // Phase B row (0..15)
    const int g    = lane & 3;        // Phase B tree group

    char* sbuf = &lds[w * WSTR];      // per-wave scratch: 16 rows x 272B
    const long grow = (long)blockIdx.x * 64;     // global row of this tile

    // ---- A-fragments straight from global (no LDS): lane(lm,lq) needs
    // x[grow+16w+lm][32s+8lq .. +7] as f32 -> f16. 8 independent dwordx4
    // loads; compiler places per-register waits -> deep miss-level overlap.
    const float* xrow = x + (grow + 16 * w + lm) * IDIM + 8 * lq;
    f32x4 xa[8];
    #pragma unroll
    for (int s = 0; s < 4; ++s) {
        xa[2 * s]     = *(const f32x4*)(xrow + 32 * s);
        xa[2 * s + 1] = *(const f32x4*)(xrow + 32 * s + 4);
    }

    // wbf resident (16 VGPR): Phase C class-weight fragment.
    half8 wbf[4];
    #pragma unroll
    for (int s = 0; s < 4; ++s)
        wbf[s] = *reinterpret_cast<const half8*>(wbT + lm * KPAD + 32 * s + 8 * lq);

    // preload nt=0 weight fragment (rotate buffer).
    half8 bfc[4], bfn[4];
    float bbc, bbn;
    {
        const _Float16* wp = wq + lm * IDIM;     // node = lm for nt=0
        #pragma unroll
        for (int s = 0; s < 4; ++s)
            bfc[s] = *reinterpret_cast<const half8*>(wp + 32 * s + 8 * lq);
        bbc = bq[lm];
    }

    // convert A to f16 fragments (frees the 32 xa VGPRs before Phase A)
    half8 af[4];
    #pragma unroll
    for (int s = 0; s < 4; ++s) {
        half8 a;
        #pragma unroll
        for (int j = 0; j < 4; ++j) {
            a[j]     = (_Float16)xa[2 * s][j];
            a[j + 4] = (_Float16)xa[2 * s + 1][j];
        }
        af[s] = a;
    }

    // ---- Phase A: z-GEMM (bias in acc init) + sigmoid -> packed cols 8t+n.
    // unroll 1 + 2-deep rotate: stops the compiler from hoisting all 7 nt
    // weight fragments into registers (R3's 128-VGPR spill lesson).
    #pragma unroll 1
    for (int nt = 0; nt < 7; ++nt) {
        if (nt + 1 < 7) {
            const _Float16* wp = wq + (16 * (nt + 1) + lm) * IDIM;
            #pragma unroll
            for (int s = 0; s < 4; ++s)
                bfn[s] = *reinterpret_cast<const half8*>(wp + 32 * s + 8 * lq);
            bbn = bq[16 * (nt + 1) + lm];
        }
        f32x4 acc = {bbc, bbc, bbc, bbc};
        #pragma unroll
        for (int s = 0; s < 4; ++s)
            acc = __builtin_amdgcn_mfma_f32_16x16x32_f16(af[s], bfc[s], acc, 0, 0, 0);
        int node = 16 * nt + lm;
        int col  = node + ((node * 9363) >> 16);   // node + node/7 = 8t+n
        #pragma unroll
        for (int r = 0; r < 4; ++r) {
            float z  = acc[r];                     // C/D: row=4lq+r, col=lm
            float sg = __builtin_amdgcn_rcpf(1.0f + __expf(-z));
            *(_Float16*)(sbuf + (4 * lq + r) * RSTR + col * 2) = (_Float16)sg;
        }
        #pragma unroll
        for (int s = 0; s < 4; ++s) bfc[s] = bfn[s];
        bbc = bbn;
    }

    // ---- Phase B: leaf probabilities (wave-lockstep, reads before writes) --
    // b128 gather: tree t=4g+tt occupies halves [8t..8t+7] = byte 16t,
    // 16B-aligned since RSTR=272=17*16. Element 7 (col 8t+7) is never
    // written by Phase A and never used here.
    {
        const char* rowp = sbuf + rg * RSTR;
        half8 hv[4];
        #pragma unroll
        for (int tt = 0; tt < 4; ++tt)
            hv[tt] = *(const half8*)(rowp + 64 * g + 16 * tt);
        half8 lv[4];
        #pragma unroll
        for (int tt = 0; tt < 4; ++tt) {
            float s0 = (float)hv[tt][0], s1 = (float)hv[tt][1], s2v = (float)hv[tt][2];
            float s3 = (float)hv[tt][3], s4 = (float)hv[tt][4], s5 = (float)hv[tt][5];
            float s6 = (float)hv[tt][6];
            float u1 = 1.f - s0, u2 = s0;
            float q1 = u1 * s1, q0 = u1 - q1;
            float q3 = u2 * s2v, q2 = u2 - q3;
            float L1 = q0 * s3, L0 = q0 - L1;
            float L3 = q1 * s4, L2 = q1 - L3;
            float L5 = q2 * s5, L4 = q2 - L5;
            float L7 = q3 * s6, L6 = q3 - L7;
            float m = (4 * g + tt < TREES) ? 1.f : 0.f;   // zero tree-15 slot
            half8 lv8;
            lv8[0] = (_Float16)(L0 * m); lv8[1] = (_Float16)(L1 * m);
            lv8[2] = (_Float16)(L2 * m); lv8[3] = (_Float16)(L3 * m);
            lv8[4] = (_Float16)(L4 * m); lv8[5] = (_Float16)(L5 * m);
            lv8[6] = (_Float16)(L6 * m); lv8[7] = (_Float16)(L7 * m);
            lv[tt] = lv8;
        }
        #pragma unroll
        for (int tt = 0; tt < 4; ++tt)
            *(half8*)(sbuf + rg * RSTR + 64 * g + 16 * tt) = lv[tt];
    }

    // ---- Phase C: leaf x wbT MFMA -> out ----
    {
        half8 af2[4];
        #pragma unroll
        for (int s = 0; s < 4; ++s)
            af2[s] = *(const half8*)(sbuf + lm * RSTR + 64 * s + 16 * lq);
        f32x4 a2 = {0.f, 0.f, 0.f, 0.f};
        #pragma unroll
        for (int s = 0; s < 4; ++s)
            a2 = __builtin_amdgcn_mfma_f32_16x16x32_f16(af2[s], wbf[s], a2, 0, 0, 0);
        if (lm < NCLS) {
            #pragma unroll
            for (int r = 0; r < 4; ++r)
                out[(grow + 16 * w + 4 * lq + r) * NCLS + lm] = a2[r];
        }
    }
}

// ---------------------------------------------------------------------------
extern "C" void kernel_launch(void* const* d_in, const int* in_sizes, int n_in,
                              void* d_out, int out_size, void* d_ws, size_t ws_size,
                              hipStream_t stream) {
    const float* x      = (const float*)d_in[0];
    const float* params = (const float*)d_in[1];
    float* out = (float*)d_out;

    _Float16* wq  = (_Float16*)d_ws;                             // 28672 B
    float*    bq  = (float*)((char*)d_ws + NPAD * IDIM * 2);     // 448 B
    _Float16* wbT = (_Float16*)((char*)bq + NPAD * 4);           // 4096 B

    const int batch = in_sizes[0] / IDIM;      // 262144
    const int tiles = batch / 64;              // 4096

    prep_kernel<<<8, 256, 0, stream>>>(params, wq, bq, wbT);
    tree_main<<<tiles, 256, 0, stream>>>(x, wq, bq, wbT, out);
}

// Round 6
// 208.388 us; speedup vs baseline: 1.1000x; 1.1000x over previous
//
#include <hip/hip_runtime.h>
#include <hip/hip_fp16.h>

// ---------------------------------------------------------------------------
// SoftDecisionTreeEnsemble: N_TREES=15, DEPTH=3, INPUT_DIM=128, N_CLASSES=10
// R8 = R4 chassis (512 persistent blocks, resident weights, 8 tiles/block;
// best measured: tree_main ~60us) + R7's x-path (direct per-lane
// global_load_dwordx4, no LDS staging, no global_load_lds, no hand vmcnt).
// Rationale: R6/R7 regressions were chassis artifacts (per-block weight
// reloads); the dur-minus-tree_main offset (142.5us, R6/R7) back-computes
// R4/R5 at ~60us. The only untested suspect on the good chassis is the
// DMA->vmcnt->ds_read chain itself; plain VGPR loads are the proven-fast
// path (fills 6.9TB/s, m13). x A-fragments double-buffer in REGISTERS
// across tiles (two named f32x4[8] arrays, static indexing, ping-pong
// lambda) -> prefetch distance = one tile wall >> HBM latency, compiler
// places exact counted waits.
//   - LDS = 17.4KB transpose scratch only (R7's layout, proven correct).
//   - VGPR ~220-240 expected; spill tripwire = WRITE_SIZE >> 10.2MB.
// ---------------------------------------------------------------------------

typedef float    f32x4 __attribute__((ext_vector_type(4)));
typedef _Float16 half8 __attribute__((ext_vector_type(8)));

#define TREES      15
#define IDIM       128
#define NCLS       10
#define NINT       7
#define NLVS       8
#define PER_TREE   (NINT*IDIM + NINT + NLVS*NCLS)   // 983
#define NODES      (TREES*NINT)                     // 105
#define NPAD       112                              // 7 n-tiles of 16
#define KPAD       128                              // leaf K padded
#define RSTR       272                              // scratch row stride bytes (136 halves)
#define WSTR       4352                             // per-wave scratch: 16 rows * 272B
#define NBLK       512                              // 2 blocks/CU

// ---------------------------------------------------------------------------
// prep: wq[112][128] f16 (row g=7t+n, zero-padded), bq[112] f32 (zero-padded),
//       wbT[16][128] f16: wbT[c][8t+l] = softmax(leaf_logits[t][l])[c]*tw[t].
// Zero padding is load-bearing: padded nodes give z=0 -> sigmoid 0.5 ->
// garbage-free; padded leaf cols/classes contribute 0.
// ---------------------------------------------------------------------------
__global__ __launch_bounds__(256) void prep_kernel(const float* __restrict__ p,
                                                   _Float16* __restrict__ wq,
                                                   float* __restrict__ bq,
                                                   _Float16* __restrict__ wbT) {
    const int gid  = blockIdx.x * 256 + threadIdx.x;
    const int nthr = gridDim.x * 256;

    for (int i = gid; i < NPAD * IDIM; i += nthr) {
        int g = i >> 7, k = i & 127;
        float v = 0.f;
        if (g < NODES) {
            int t = g / NINT, n = g % NINT;
            v = p[t * PER_TREE + n * IDIM + k];
        }
        wq[i] = (_Float16)v;
    }
    for (int i = gid; i < NPAD; i += nthr) {
        float v = 0.f;
        if (i < NODES) {
            int t = i / NINT, n = i % NINT;
            v = p[t * PER_TREE + NINT * IDIM + n];
        }
        bq[i] = v;
    }
    const float* tl = p + TREES * PER_TREE;
    for (int i = gid; i < 16 * KPAD; i += nthr) {
        int c = i >> 7, k = i & 127;
        float v = 0.f;
        if (c < NCLS && k < TREES * NLVS) {
            int t = k >> 3, l = k & 7;
            const float* ll = p + t * PER_TREE + NINT * IDIM + NINT + l * NCLS;
            float mx = ll[0];
            #pragma unroll
            for (int j = 1; j < NCLS; ++j) mx = fmaxf(mx, ll[j]);
            float se = 0.f;
            #pragma unroll
            for (int j = 0; j < NCLS; ++j) se += __expf(ll[j] - mx);
            float lsm = __expf(ll[c] - mx) / se;

            float m2 = tl[0];
            #pragma unroll
            for (int j = 1; j < TREES; ++j) m2 = fmaxf(m2, tl[j]);
            float s2 = 0.f;
            #pragma unroll
            for (int j = 0; j < TREES; ++j) s2 += __expf(tl[j] - m2);
            float tw = __expf(tl[t] - m2) / s2;
            v = lsm * tw;
        }
        wbT[i] = (_Float16)v;
    }
}

// load one tile's A-fragment data for this lane: x[row][32s+8lq .. +7]
__device__ __forceinline__ void load_xa(const float* __restrict__ xr,
                                        f32x4 (&xa)[8]) {
    #pragma unroll
    for (int s = 0; s < 4; ++s) {
        xa[2 * s]     = *(const f32x4*)(xr + 32 * s);
        xa[2 * s + 1] = *(const f32x4*)(xr + 32 * s + 4);
    }
}

// ---------------------------------------------------------------------------
__global__ __launch_bounds__(256, 2) void tree_main(const float* __restrict__ x,
                                                    const _Float16* __restrict__ wq,
                                                    const float* __restrict__ bq,
                                                    const _Float16* __restrict__ wbT,
                                                    float* __restrict__ out,
                                                    int tpb) {
    __shared__ __align__(16) char lds[4 * WSTR];    // 17408 B scratch

    const int tid  = threadIdx.x;
    const int lane = tid & 63;
    const int w    = tid >> 6;        // wave id: owns tile rows 16w..16w+15
    const int lm   = lane & 15;
    const int lq   = lane >> 4;
    const int rg   = lane >> 2;       // Phase B row (0..15)
    const int g    = lane & 3;        // Phase B tree group

    char* sbuf = &lds[w * WSTR];      // per-wave scratch: 16 rows x 272B
    const long tile0 = (long)blockIdx.x * tpb;

    // this lane's x pointer for tile 0; advances 64*IDIM floats per tile
    const float* xlane = x + (tile0 * 64 + 16 * w + lm) * IDIM + 8 * lq;

    // prefetch tile 0 A-data into registers (overlaps weight loads below)
    f32x4 xaA[8], xaB[8];
    load_xa(xlane, xaA);

    // resident weights: B-frags (7 n-tiles), biases, class weights.
    // Packed f16 -> plain half8 vector loads (R3 spill lesson).
    half8 bf[7][4];
    float bb[7];
    #pragma unroll
    for (int nt = 0; nt < 7; ++nt) {
        bb[nt] = bq[16 * nt + lm];
        #pragma unroll
        for (int s = 0; s < 4; ++s)
            bf[nt][s] = *reinterpret_cast<const half8*>(wq + (16 * nt + lm) * IDIM + 32 * s + 8 * lq);
    }
    half8 wbf[4];
    #pragma unroll
    for (int s = 0; s < 4; ++s)
        wbf[s] = *reinterpret_cast<const half8*>(wbT + lm * KPAD + 32 * s + 8 * lq);

    // one tile's full pipeline; xac = this tile's (already loaded) A-data,
    // xan = next tile's buffer to prefetch into. Static indexing throughout.
    auto tile_body = [&](int i, f32x4 (&xac)[8], f32x4 (&xan)[8]) {
        const long grow = (tile0 + i) * 64;

        // convert A to f16 fragments (waits on xac loads, issued 1 tile ago)
        half8 af[4];
        #pragma unroll
        for (int s = 0; s < 4; ++s) {
            half8 a;
            #pragma unroll
            for (int j = 0; j < 4; ++j) {
                a[j]     = (_Float16)xac[2 * s][j];
                a[j + 4] = (_Float16)xac[2 * s + 1][j];
            }
            af[s] = a;
        }

        // prefetch next tile's A-data (one full tile wall ahead of use)
        if (i + 1 < tpb)
            load_xa(xlane + (long)(i + 1) * 64 * IDIM, xan);

        // ---- Phase A: z-GEMM (bias in acc init) + sigmoid -> packed cols 8t+n
        #pragma unroll
        for (int nt = 0; nt < 7; ++nt) {
            f32x4 acc = {bb[nt], bb[nt], bb[nt], bb[nt]};
            #pragma unroll
            for (int s = 0; s < 4; ++s)
                acc = __builtin_amdgcn_mfma_f32_16x16x32_f16(af[s], bf[nt][s], acc, 0, 0, 0);
            int node = 16 * nt + lm;
            int col  = node + ((node * 9363) >> 16);   // node + node/7 = 8t+n
            #pragma unroll
            for (int r = 0; r < 4; ++r) {
                float z  = acc[r];                     // C/D: row=4lq+r, col=lm
                float sg = __builtin_amdgcn_rcpf(1.0f + __expf(-z));
                *(_Float16*)(sbuf + (4 * lq + r) * RSTR + col * 2) = (_Float16)sg;
            }
        }

        // ---- Phase B: leaf probabilities (wave-lockstep, reads before writes)
        // b128 gather: tree t=4g+tt at halves [8t..8t+7] = byte 16t,
        // 16B-aligned since RSTR=272=17*16.
        {
            const char* rowp = sbuf + rg * RSTR;
            half8 hv[4];
            #pragma unroll
            for (int tt = 0; tt < 4; ++tt)
                hv[tt] = *(const half8*)(rowp + 64 * g + 16 * tt);
            half8 lv[4];
            #pragma unroll
            for (int tt = 0; tt < 4; ++tt) {
                float s0 = (float)hv[tt][0], s1 = (float)hv[tt][1], s2v = (float)hv[tt][2];
                float s3 = (float)hv[tt][3], s4 = (float)hv[tt][4], s5 = (float)hv[tt][5];
                float s6 = (float)hv[tt][6];
                float u1 = 1.f - s0, u2 = s0;
                float q1 = u1 * s1, q0 = u1 - q1;
                float q3 = u2 * s2v, q2 = u2 - q3;
                float L1 = q0 * s3, L0 = q0 - L1;
                float L3 = q1 * s4, L2 = q1 - L3;
                float L5 = q2 * s5, L4 = q2 - L5;
                float L7 = q3 * s6, L6 = q3 - L7;
                float m = (4 * g + tt < TREES) ? 1.f : 0.f;   // zero tree-15 slot
                half8 lv8;
                lv8[0] = (_Float16)(L0 * m); lv8[1] = (_Float16)(L1 * m);
                lv8[2] = (_Float16)(L2 * m); lv8[3] = (_Float16)(L3 * m);
                lv8[4] = (_Float16)(L4 * m); lv8[5] = (_Float16)(L5 * m);
                lv8[6] = (_Float16)(L6 * m); lv8[7] = (_Float16)(L7 * m);
                lv[tt] = lv8;
            }
            #pragma unroll
            for (int tt = 0; tt < 4; ++tt)
                *(half8*)(sbuf + rg * RSTR + 64 * g + 16 * tt) = lv[tt];
        }

        // ---- Phase C: leaf x wbT MFMA -> out ----
        {
            half8 af2[4];
            #pragma unroll
            for (int s = 0; s < 4; ++s)
                af2[s] = *(const half8*)(sbuf + lm * RSTR + 64 * s + 16 * lq);
            f32x4 a2 = {0.f, 0.f, 0.f, 0.f};
            #pragma unroll
            for (int s = 0; s < 4; ++s)
                a2 = __builtin_amdgcn_mfma_f32_16x16x32_f16(af2[s], wbf[s], a2, 0, 0, 0);
            if (lm < NCLS) {
                #pragma unroll
                for (int r = 0; r < 4; ++r)
                    out[(grow + 16 * w + 4 * lq + r) * NCLS + lm] = a2[r];
            }
        }
    };

    // ping-pong over tiles (tpb is even); static buffer names at each site.
    for (int i = 0; i < tpb; i += 2) {
        tile_body(i,     xaA, xaB);
        tile_body(i + 1, xaB, xaA);
    }
}

// ---------------------------------------------------------------------------
extern "C" void kernel_launch(void* const* d_in, const int* in_sizes, int n_in,
                              void* d_out, int out_size, void* d_ws, size_t ws_size,
                              hipStream_t stream) {
    const float* x      = (const float*)d_in[0];
    const float* params = (const float*)d_in[1];
    float* out = (float*)d_out;

    _Float16* wq  = (_Float16*)d_ws;                             // 28672 B
    float*    bq  = (float*)((char*)d_ws + NPAD * IDIM * 2);     // 448 B
    _Float16* wbT = (_Float16*)((char*)bq + NPAD * 4);           // 4096 B

    const int batch = in_sizes[0] / IDIM;      // 262144
    const int tiles = batch / 64;              // 4096
    const int tpb   = tiles / NBLK;            // 8

    prep_kernel<<<8, 256, 0, stream>>>(params, wq, bq, wbT);
    tree_main<<<NBLK, 256, 0, stream>>>(x, wq, bq, wbT, out, tpb);
}